// Round 4
// baseline (662.865 us; speedup 1.0000x reference)
//
#include <hip/hip_runtime.h>

#define STRIDE 264     // LDS row stride in floats (256 valid + 8 pad for float4 overreads)
#define S_TILE 244     // output positions per block; S_TILE+12 = 256 = widest intermediate
#define W_IN   258     // S_TILE + 14 (halo 7 each side)
#define SEQ    8192
#define NTHR   512     // 8 waves; wave owns 4 channels, lane owns 4 positions

__device__ __forceinline__ int uni(int v) { return __builtin_amdgcn_readfirstlane(v); }

// One conv(k)+bias+relu+BN layer: in/out are LDS [C][STRIDE].
// Wave owns 4 consecutive output channels (cobase wave-uniform -> scalar weight loads),
// lane owns 4 consecutive positions p0..p0+3 (p0 = 4*lane, 16B aligned).
// Window loads are software-pipelined 2 deep (ping-pong buf0/buf1): loads for
// ci+2/ci+3 are issued before the FMAs of ci/ci+1, hiding ~120cyc LDS latency
// (K=3 layers have only ~96 FMA-cycles/iter -> distance 1 is not enough).
// DOFF: global position of output local index 0 is s0 + DOFF; outside [0,SEQ) -> 0
// to match the reference's per-layer zero padding.
template<int CIN, int K, int DOFF>
__device__ __forceinline__ void conv_bn_relu(
    const float* __restrict__ w, const float* __restrict__ bias,
    const float* __restrict__ g, const float* __restrict__ bb,
    const float* __restrict__ rm, const float* __restrict__ rv,
    const float* in, float* out, int cobase, int p0, int s0)
{
    constexpr int WINN = ((K + 3 + 3) / 4) * 4;   // window floats, rounded to float4
    constexpr int NV   = WINN / 4;                // float4 loads per window (2 or 3)
    static_assert(CIN % 2 == 0, "ping-pong assumes even CIN");

    float acc[4][4];
#pragma unroll
    for (int j = 0; j < 4; ++j) {
        float bj = bias[cobase + j];
#pragma unroll
        for (int i = 0; i < 4; ++i) acc[j][i] = bj;
    }

    const float* rowb = in + p0;
    float4 buf0[NV], buf1[NV];
#pragma unroll
    for (int v = 0; v < NV; ++v) buf0[v] = *(const float4*)(rowb + 0 * STRIDE + 4 * v);
#pragma unroll
    for (int v = 0; v < NV; ++v) buf1[v] = *(const float4*)(rowb + 1 * STRIDE + 4 * v);

#pragma unroll
    for (int ci = 0; ci < CIN; ci += 2) {
        // ---- even sub-iteration: consume buf0, prefetch ci+2 into buf0 ----
        float win[WINN];
#pragma unroll
        for (int v = 0; v < NV; ++v) {
            win[4*v+0] = buf0[v].x; win[4*v+1] = buf0[v].y;
            win[4*v+2] = buf0[v].z; win[4*v+3] = buf0[v].w;
        }
        if (ci + 2 < CIN) {
#pragma unroll
            for (int v = 0; v < NV; ++v)
                buf0[v] = *(const float4*)(rowb + (ci + 2) * STRIDE + 4 * v);
        }
#pragma unroll
        for (int j = 0; j < 4; ++j) {
            const float* wp = w + ((cobase + j) * CIN + ci) * K;  // uniform address
#pragma unroll
            for (int k = 0; k < K; ++k) {
                float wv = wp[k];
#pragma unroll
                for (int i = 0; i < 4; ++i)
                    acc[j][i] = fmaf(win[k + i], wv, acc[j][i]);
            }
        }
        // ---- odd sub-iteration: consume buf1, prefetch ci+3 into buf1 ----
#pragma unroll
        for (int v = 0; v < NV; ++v) {
            win[4*v+0] = buf1[v].x; win[4*v+1] = buf1[v].y;
            win[4*v+2] = buf1[v].z; win[4*v+3] = buf1[v].w;
        }
        if (ci + 3 < CIN) {
#pragma unroll
            for (int v = 0; v < NV; ++v)
                buf1[v] = *(const float4*)(rowb + (ci + 3) * STRIDE + 4 * v);
        }
#pragma unroll
        for (int j = 0; j < 4; ++j) {
            const float* wp = w + ((cobase + j) * CIN + ci + 1) * K;
#pragma unroll
            for (int k = 0; k < K; ++k) {
                float wv = wp[k];
#pragma unroll
                for (int i = 0; i < 4; ++i)
                    acc[j][i] = fmaf(win[k + i], wv, acc[j][i]);
            }
        }
    }

    // BN (inference) epilogue: relu -> *scale + shift; zero outside sequence; b128 store.
#pragma unroll
    for (int j = 0; j < 4; ++j) {
        int co = cobase + j;
        float scale = g[co] / sqrtf(rv[co] + 1e-5f);
        float shift = bb[co] - rm[co] * scale;
        float4 vv;
#pragma unroll
        for (int i = 0; i < 4; ++i) {
            float v = fmaxf(acc[j][i], 0.0f) * scale + shift;
            if ((unsigned)(s0 + DOFF + p0 + i) >= SEQ) v = 0.0f;
            (&vv.x)[i] = v;
        }
        *(float4*)(out + co * STRIDE + p0) = vv;   // 16B/lane
    }
}

extern "C" __global__ void __launch_bounds__(NTHR, 4)
dnashape_fused(const float* __restrict__ x,
    const float* __restrict__ w0, const float* __restrict__ b0, const float* __restrict__ g0,
    const float* __restrict__ bb0, const float* __restrict__ rm0, const float* __restrict__ rv0,
    const float* __restrict__ w1, const float* __restrict__ b1, const float* __restrict__ g1,
    const float* __restrict__ bb1, const float* __restrict__ rm1, const float* __restrict__ rv1,
    const float* __restrict__ w2, const float* __restrict__ b2, const float* __restrict__ g2,
    const float* __restrict__ bb2, const float* __restrict__ rm2, const float* __restrict__ rv2,
    const float* __restrict__ w3, const float* __restrict__ b3, const float* __restrict__ g3,
    const float* __restrict__ bb3, const float* __restrict__ rm3, const float* __restrict__ rv3,
    const float* __restrict__ fw1, const float* __restrict__ fb1,
    const float* __restrict__ fw2, const float* __restrict__ fb2,
    float* __restrict__ out)
{
    // bufB doubles as the input buffer (rows 0..3) for layer 0; layer 1 overwrites
    // it only after layer 0 consumed it. Total LDS = 64 rows = 67.6 KB -> 2 blocks/CU.
    __shared__ float bufA[32 * STRIDE];
    __shared__ float bufB[32 * STRIDE];

    const int tile = blockIdx.x;
    const int b    = blockIdx.y;
    const int s0   = tile * S_TILE;
    const int base = s0 - 7;            // input buffer origin (halo 7)
    const int tid  = threadIdx.x;

    // Stage 0: global -> LDS input tile (into bufB rows 0..3), zero-padded at edges
#pragma unroll
    for (int c = 0; c < 4; ++c) {
        for (int i = tid; i < W_IN; i += NTHR) {
            int sg = base + i;
            float v = (sg >= 0 && sg < SEQ) ? x[(b * 4 + c) * SEQ + sg] : 0.0f;
            bufB[c * STRIDE + i] = v;
        }
    }
    __syncthreads();

    const int wave   = uni(tid >> 6);   // wave-uniform for scalar weight loads
    const int lane   = tid & 63;
    const int cobase = wave * 4;        // 8 waves x 4 channels = 32
    const int p0     = lane * 4;

    // Buffer origins: in = s0-7, L0out = s0-6, L1out = s0-5, L2out = s0-3, L3out = s0.
    conv_bn_relu<4,  3, -6>(w0, b0, g0, bb0, rm0, rv0, bufB, bufA, cobase, p0, s0);
    __syncthreads();
    conv_bn_relu<32, 3, -5>(w1, b1, g1, bb1, rm1, rv1, bufA, bufB, cobase, p0, s0);
    __syncthreads();
    conv_bn_relu<32, 5, -3>(w2, b2, g2, bb2, rm2, rv2, bufB, bufA, cobase, p0, s0);
    __syncthreads();
    conv_bn_relu<32, 7,  0>(w3, b3, g3, bb3, rm3, rv3, bufA, bufB, cobase, p0, s0);
    __syncthreads();

    // Stage 5: per-position MLP 32 -> 16 (relu) -> 1
    if (tid < S_TILE) {
        int s = s0 + tid;
        if (s < SEQ) {
            float xv[32];
#pragma unroll
            for (int c = 0; c < 32; ++c) xv[c] = bufB[c * STRIDE + tid];
            float o = fb2[0];
#pragma unroll
            for (int h = 0; h < 16; ++h) {
                float a = fb1[h];
#pragma unroll
                for (int c = 0; c < 32; ++c) a = fmaf(xv[c], fw1[h * 32 + c], a);
                o = fmaf(fmaxf(a, 0.0f), fw2[h], o);
            }
            out[b * SEQ + s] = o;
        }
    }
}

extern "C" void kernel_launch(void* const* d_in, const int* in_sizes, int n_in,
                              void* d_out, int out_size, void* d_ws, size_t ws_size,
                              hipStream_t stream) {
    const float* p[29];
    for (int i = 0; i < 29; ++i) p[i] = (const float*)d_in[i];
    dim3 grid((SEQ + S_TILE - 1) / S_TILE, 128);   // 34 x 128
    dnashape_fused<<<grid, NTHR, 0, stream>>>(p[0],
        p[1],  p[2],  p[3],  p[4],  p[5],  p[6],
        p[7],  p[8],  p[9],  p[10], p[11], p[12],
        p[13], p[14], p[15], p[16], p[17], p[18],
        p[19], p[20], p[21], p[22], p[23], p[24],
        p[25], p[26], p[27], p[28],
        (float*)d_out);
}

// Round 5
// 205.831 us; speedup vs baseline: 3.2204x; 3.2204x over previous
//
#include <hip/hip_runtime.h>

#define SEQ    8192
#define S_TILE 244            // valid output positions per 256-pos tile
#define NROW   264            // LDS rows (positions) per chunk
#define CS     2120           // chunk stride in halves (264*8=2112, +8 bank-skew -> quads hit disjoint banks)
#define NTHR   512            // 8 waves; wave owns 2 n-tiles x both m-halves
#define NREC   37             // 36 conv A-records + 1 MLP record (each 64 lanes x 16B = 1KB)
#define BN_HALFOFF (NREC*512) // BN region offset (in halves) inside d_ws

typedef __attribute__((ext_vector_type(8))) _Float16 half8;
typedef __attribute__((ext_vector_type(4))) _Float16 half4v;
typedef __attribute__((ext_vector_type(4))) float    f32x4;

__device__ __forceinline__ int uni(int v){ return __builtin_amdgcn_readfirstlane(v); }

// ---------------- prep: weights -> A-fragment-ready f16 records + folded BN ----------------
// Record (tap, mh): lane l holds A[m][k] = W[co=mh*16+(l&15)][ci=(l>>4)*8+j][tap], j=0..7
// (A-operand layout for mfma_f32_16x16x32: A[m=lane&15][k=quad*8+j], guide m120).
extern "C" __global__ void prep_kernel(
    const float* w0, const float* w1, const float* w2, const float* w3,
    const float* b0, const float* g0, const float* bb0, const float* rm0, const float* rv0,
    const float* b1, const float* g1, const float* bb1, const float* rm1, const float* rv1,
    const float* b2, const float* g2, const float* bb2, const float* rm2, const float* rv2,
    const float* b3, const float* g3, const float* bb3, const float* rm3, const float* rv3,
    const float* fw1, _Float16* ws)
{
    const int tid  = threadIdx.x;
    const int lane = tid & 63;
    for (int rec = tid >> 6; rec < NREC; rec += 4) {
        const float* W; int CIN, K, r2;
        if      (rec < 6)  { W = w0;  CIN = 4;  K = 3; r2 = rec;      }
        else if (rec < 12) { W = w1;  CIN = 32; K = 3; r2 = rec - 6;  }
        else if (rec < 22) { W = w2;  CIN = 32; K = 5; r2 = rec - 12; }
        else if (rec < 36) { W = w3;  CIN = 32; K = 7; r2 = rec - 22; }
        else               { W = fw1; CIN = 32; K = 1; r2 = 0;        }
        int tap = r2 >> 1, mh = r2 & 1;
        int co  = mh*16 + (lane & 15);
        int ci0 = (lane >> 4) * 8;
        half8 h;
#pragma unroll
        for (int j = 0; j < 8; ++j) {
            int ci = ci0 + j;
            float wv = (ci < CIN) ? W[(co*CIN + ci)*K + tap] : 0.0f;
            h[j] = (_Float16)wv;
        }
        *(half8*)(ws + rec*512 + lane*8) = h;
    }
    // Folded BN: per (layer, co): scale = g/sqrt(rv+eps), shift = bb - rm*scale, bias.
    if (tid < 128) {
        int l = tid >> 5, co = tid & 31;
        const float *g, *bb, *rm, *rv, *bi;
        if      (l == 0) { g=g0; bb=bb0; rm=rm0; rv=rv0; bi=b0; }
        else if (l == 1) { g=g1; bb=bb1; rm=rm1; rv=rv1; bi=b1; }
        else if (l == 2) { g=g2; bb=bb2; rm=rm2; rv=rv2; bi=b2; }
        else             { g=g3; bb=bb3; rm=rm3; rv=rv3; bi=b3; }
        float scale = g[co] / sqrtf(rv[co] + 1e-5f);
        float shift = bb[co] - rm[co]*scale;
        float* bn = (float*)(ws + BN_HALFOFF) + (l*32 + co)*4;
        bn[0] = scale; bn[1] = shift; bn[2] = bi[co]; bn[3] = 0.0f;
    }
}

// ---------------- one conv layer via MFMA ----------------
// in/out: LDS f16, 4 chunks x NROW pos x 8 halves (chunk cb holds ci 8cb..8cb+7).
// B-frag (lane l): pos = base+(l&15)+tap, ci = (l>>4)*8+j -> one b128 at q*CS + pos*8.
// D (C/D layout, m89/m121-128): col=lane&15 -> pos, row=q*4+r -> co (within m-half).
// DOFF: global pos of local 0 = s0+DOFF; outside [0,SEQ) forced to 0 (ref zero-pads each layer).
template<int K, int DOFF>
__device__ __forceinline__ void conv_layer(
    const _Float16* __restrict__ rec, const float4* __restrict__ bn,
    const _Float16* in, _Float16* outb, int s0, int ntb, int lane)
{
    const int q = lane >> 4, n = lane & 15;
    f32x4 acc[2][2];
#pragma unroll
    for (int nt = 0; nt < 2; ++nt)
#pragma unroll
        for (int mh = 0; mh < 2; ++mh) acc[nt][mh] = (f32x4){0.f, 0.f, 0.f, 0.f};

#pragma unroll
    for (int tap = 0; tap < K; ++tap) {
        half8 a0 = *(const half8*)(rec + (tap*2 + 0)*512 + lane*8);
        half8 a1 = *(const half8*)(rec + (tap*2 + 1)*512 + lane*8);
#pragma unroll
        for (int nt = 0; nt < 2; ++nt) {
            int pos = (ntb + nt)*16 + n + tap;
            half8 bf = *(const half8*)(in + q*CS + pos*8);
            acc[nt][0] = __builtin_amdgcn_mfma_f32_16x16x32_f16(a0, bf, acc[nt][0], 0, 0, 0);
            acc[nt][1] = __builtin_amdgcn_mfma_f32_16x16x32_f16(a1, bf, acc[nt][1], 0, 0, 0);
        }
    }
    // epilogue: relu(acc+bias)*scale+shift, seq-edge zero, pack 4 co -> one b64 LDS write
#pragma unroll
    for (int nt = 0; nt < 2; ++nt) {
        int pos = (ntb + nt)*16 + n;
        bool oob = (unsigned)(s0 + DOFF + pos) >= SEQ;
#pragma unroll
        for (int mh = 0; mh < 2; ++mh) {
            int co0 = mh*16 + q*4;
            half4v hv;
#pragma unroll
            for (int r = 0; r < 4; ++r) {
                float4 p = bn[co0 + r];
                float v = fmaxf(acc[nt][mh][r] + p.z, 0.0f)*p.x + p.y;
                if (oob) v = 0.0f;
                hv[r] = (_Float16)v;
            }
            int cb = mh*2 + (q >> 1);
            *(half4v*)(outb + cb*CS + pos*8 + (q & 1)*4) = hv;
        }
    }
}

extern "C" __global__ void __launch_bounds__(NTHR, 6)
dnashape_mfma(const float* __restrict__ x, const _Float16* __restrict__ ws,
              const float* __restrict__ fb1, const float* __restrict__ fw2,
              const float* __restrict__ fb2, float* __restrict__ out)
{
    __shared__ _Float16 bufA[4*CS];
    __shared__ _Float16 bufB[4*CS];

    const int tid  = threadIdx.x;
    const int tile = blockIdx.x, b = blockIdx.y;
    const int s0   = tile * S_TILE;

    // Stage input into bufB: chunk0 = f16(x[ci 0..3]) + 4 zeros, chunks 1-3 zero.
    const half8 z8 = {0,0,0,0,0,0,0,0};
    for (int li = tid; li < NROW; li += NTHR) {
        int sg = s0 - 7 + li;   // input origin s0-7 (halo 7)
        bool ok = (unsigned)sg < SEQ;
        float v0 = ok ? x[(b*4 + 0)*SEQ + sg] : 0.f;
        float v1 = ok ? x[(b*4 + 1)*SEQ + sg] : 0.f;
        float v2 = ok ? x[(b*4 + 2)*SEQ + sg] : 0.f;
        float v3 = ok ? x[(b*4 + 3)*SEQ + sg] : 0.f;
        half8 h0 = {(_Float16)v0, (_Float16)v1, (_Float16)v2, (_Float16)v3, 0, 0, 0, 0};
        *(half8*)(bufB + 0*CS + li*8) = h0;
        *(half8*)(bufB + 1*CS + li*8) = z8;
        *(half8*)(bufB + 2*CS + li*8) = z8;
        *(half8*)(bufB + 3*CS + li*8) = z8;
    }
    // Zero bufA halo rows 256..263 (read by later layers, written by none).
    if (tid < 32) *(half8*)(bufA + (tid >> 3)*CS + (256 + (tid & 7))*8) = z8;
    __syncthreads();

    const int lane = tid & 63;
    const int ntb  = uni(tid >> 6) * 2;     // wave-uniform n-tile base
    const float4* bn = (const float4*)(ws + BN_HALFOFF);

    // Buffer origins: in=s0-7, L0out=s0-6, L1out=s0-5, L2out=s0-3, L3out=s0.
    conv_layer<3, -6>(ws +  0*512, bn +  0, bufB, bufA, s0, ntb, lane);
    __syncthreads();
    conv_layer<3, -5>(ws +  6*512, bn + 32, bufA, bufB, s0, ntb, lane);
    __syncthreads();
    conv_layer<5, -3>(ws + 12*512, bn + 64, bufB, bufA, s0, ntb, lane);
    __syncthreads();
    conv_layer<7,  0>(ws + 22*512, bn + 96, bufA, bufB, s0, ntb, lane);
    __syncthreads();

    // MLP 32 -> 16 (relu) -> 1: one MFMA per n-tile; D row = h, col = pos.
    {
        const int q = lane >> 4, n = lane & 15;
        half8 am = *(const half8*)(ws + 36*512 + lane*8);
        float fb1v[4], fw2v[4];
#pragma unroll
        for (int r = 0; r < 4; ++r) { fb1v[r] = fb1[q*4 + r]; fw2v[r] = fw2[q*4 + r]; }
        float fb2v = fb2[0];
#pragma unroll
        for (int nt = 0; nt < 2; ++nt) {
            int pos = (ntb + nt)*16 + n;
            half8 bf = *(const half8*)(bufB + q*CS + pos*8);
            f32x4 d = {0.f, 0.f, 0.f, 0.f};
            d = __builtin_amdgcn_mfma_f32_16x16x32_f16(am, bf, d, 0, 0, 0);
            float part = 0.f;
#pragma unroll
            for (int r = 0; r < 4; ++r) part += fmaxf(d[r] + fb1v[r], 0.f)*fw2v[r];
            part += __shfl_xor(part, 16, 64);   // reduce across the 4 quads (h-blocks)
            part += __shfl_xor(part, 32, 64);
            if (lane < 16) {
                int g = s0 + pos;
                if (pos < S_TILE && g < SEQ) out[b*SEQ + g] = part + fb2v;
            }
        }
    }
}

extern "C" void kernel_launch(void* const* d_in, const int* in_sizes, int n_in,
                              void* d_out, int out_size, void* d_ws, size_t ws_size,
                              hipStream_t stream) {
    const float* p[29];
    for (int i = 0; i < 29; ++i) p[i] = (const float*)d_in[i];
    _Float16* ws = (_Float16*)d_ws;   // needs 37*1024 + 2048 = 39936 B

    prep_kernel<<<1, 256, 0, stream>>>(
        p[1], p[7], p[13], p[19],
        p[2], p[3], p[4], p[5], p[6],
        p[8], p[9], p[10], p[11], p[12],
        p[14], p[15], p[16], p[17], p[18],
        p[20], p[21], p[22], p[23], p[24],
        p[25], ws);

    dim3 grid((SEQ + S_TILE - 1) / S_TILE, 128);   // 34 x 128
    dnashape_mfma<<<grid, NTHR, 0, stream>>>(p[0], (const _Float16*)ws,
                                             p[26], p[27], p[28], (float*)d_out);
}